// Round 14
// baseline (2521.134 us; speedup 1.0000x reference)
//
#include <hip/hip_runtime.h>
#include <cstdint>
#include <cstddef>

#define ZB 512
#define ZT 256
#define ZIN 64
#define ZEH 128
#define ZH 512
#define ZG 2048
#define ZNC 8
#define NBLK 256

typedef __attribute__((ext_vector_type(8))) short s8v;
typedef __attribute__((ext_vector_type(4))) float f4v;
typedef unsigned short u16;
typedef unsigned int u32;
typedef unsigned long long u64;

__device__ __forceinline__ u16 f2bf(float f){
  u32 u = __builtin_bit_cast(u32, f);
  u += 0x7FFFu + ((u >> 16) & 1u);
  return (u16)(u >> 16);
}
__device__ __forceinline__ s8v pair2v(u64 a, u64 b){
  union { u64 q[2]; s8v v; } u; u.q[0] = a; u.q[1] = b; return u.v;
}
// h layout: [buf2][bg8][half2][hg32][32 rows][16 cols] u16; chunk = 1KB/hg
__device__ __forceinline__ size_t qoff2(int buf, int bg, int hf, int hg){
  return ((((size_t)buf * 8 + bg) * 2 + hf) * 32 + hg) * 512;   // u16 elements
}
__device__ __forceinline__ u64 aload(const u64* p){
  return __hip_atomic_load(p, __ATOMIC_RELAXED, __HIP_MEMORY_SCOPE_AGENT);
}
__device__ __forceinline__ float rcpf(float x){
  return __builtin_amdgcn_rcpf(x);   // native 1/x, ~1ulp — gates tolerate it
}

// ---------------------------------------------------------------------------
// Fold: Wc[2048][128] = W_ih @ W2 (bf16), bc[2048] = W_ih@b2 + b_ih + b_hh
// ---------------------------------------------------------------------------
__global__ __launch_bounds__(128)
void k_fold(const float* __restrict__ W_ih, const float* __restrict__ W2,
            const float* __restrict__ b2, const float* __restrict__ b_ih,
            const float* __restrict__ b_hh, u16* __restrict__ Wc,
            float* __restrict__ bc)
{
  const int r = blockIdx.x, c = threadIdx.x;
  const float* wr = W_ih + (size_t)r * ZH;
  float acc = 0.f;
  for (int k = 0; k < ZH; ++k) acc += wr[k] * W2[(size_t)k * ZEH + c];
  Wc[(size_t)r * ZEH + c] = f2bf(acc);
  __shared__ float red[128];
  float p = 0.f;
  for (int k = c; k < ZH; k += 128) p += wr[k] * b2[k];
  red[c] = p; __syncthreads();
  for (int s = 64; s > 0; s >>= 1){ if (c < s) red[c] += red[c + s]; __syncthreads(); }
  if (c == 0) bc[r] = red[0] + b_ih[r] + b_hh[r];
}

__global__ __launch_bounds__(256)
void k_cvt(const float* __restrict__ src, u16* __restrict__ dst, int n)
{
  int i = blockIdx.x * 256 + threadIdx.x;
  if (i < n) dst[i] = f2bf(src[i]);
}

// ---------------------------------------------------------------------------
// Encoder layer 1: X1 (t-major: [T][B][128]) = bf16(LeakyReLU(seq@W1^T+b1))
// ---------------------------------------------------------------------------
__global__ __launch_bounds__(256)
void k_enc(const float* __restrict__ seq, const float* __restrict__ W1,
           const float* __restrict__ b1, u16* __restrict__ X1)
{
  __shared__ float w1s[ZEH * 65];
  __shared__ float sqs[64 * 65];
  const int tid = threadIdx.x;
  const size_t rb = (size_t)blockIdx.x * 64;
  for (int i = tid; i < ZEH * ZIN; i += 256){ int r = i >> 6, c = i & 63; w1s[r * 65 + c] = W1[i]; }
  for (int i = tid; i < 64 * ZIN; i += 256){ int r = i >> 6, c = i & 63; sqs[r * 65 + c] = seq[(rb + r) * ZIN + c]; }
  __syncthreads();
  const int cg = tid & 31, rg = tid >> 5;
  float acc[8][4];
  #pragma unroll
  for (int i = 0; i < 8; ++i){
    #pragma unroll
    for (int j = 0; j < 4; ++j) acc[i][j] = 0.f;
  }
  for (int k = 0; k < ZIN; ++k){
    float wv[4], sv[8];
    #pragma unroll
    for (int j = 0; j < 4; ++j) wv[j] = w1s[(cg * 4 + j) * 65 + k];
    #pragma unroll
    for (int i = 0; i < 8; ++i) sv[i] = sqs[(rg * 8 + i) * 65 + k];
    #pragma unroll
    for (int i = 0; i < 8; ++i){
      #pragma unroll
      for (int j = 0; j < 4; ++j) acc[i][j] += sv[i] * wv[j];
    }
  }
  #pragma unroll
  for (int i = 0; i < 8; ++i){
    ushort4 pk;
    float v0 = acc[i][0] + b1[cg * 4 + 0]; v0 = v0 > 0.f ? v0 : 0.01f * v0;
    float v1 = acc[i][1] + b1[cg * 4 + 1]; v1 = v1 > 0.f ? v1 : 0.01f * v1;
    float v2 = acc[i][2] + b1[cg * 4 + 2]; v2 = v2 > 0.f ? v2 : 0.01f * v2;
    float v3 = acc[i][3] + b1[cg * 4 + 3]; v3 = v3 > 0.f ? v3 : 0.01f * v3;
    pk.x = f2bf(v0); pk.y = f2bf(v1); pk.z = f2bf(v2); pk.w = f2bf(v3);
    int rf = (int)rb + rg * 8 + i;            // flat b*T + t
    int b = rf >> 8, tt = rf & 255;
    *(ushort4*)(X1 + ((size_t)tt * ZB + b) * ZEH + cg * 4) = pk;
  }
}

// ---------------------------------------------------------------------------
// half wait: lane l polls flag[gidx][l&31] (agent scope / MALL); flag value
// is the SUM of per-wave atomic publishes: target = 4 * step.
// ---------------------------------------------------------------------------
__device__ __forceinline__ void qwait(const u32* flags, int gidx, u32 target)
{
  const int l = threadIdx.x & 63;
  const u32* fp = flags + ((size_t)(gidx * 32 + (l & 31))) * 16;
  long long guard = 0;
  for (;;){
    u32 v = __hip_atomic_load(fp, __ATOMIC_RELAXED, __HIP_MEMORY_SCOPE_AGENT);
    if (__ballot(v >= target) == ~0ull) break;
    __builtin_amdgcn_s_sleep(1);
    if (++guard > (1LL << 20)) break;   // fail loud (wrong answer), never hang
  }
}

#define RAWBAR() do{ asm volatile("s_waitcnt lgkmcnt(0)" ::: "memory"); \
                     __builtin_amdgcn_s_barrier();                      \
                     __builtin_amdgcn_sched_barrier(0); }while(0)

// ---------------------------------------------------------------------------
// Cooperative LSTM, 2-slot ring, TOP-COMMIT structure (r12 + chain split):
//   phase A (slot top): stage commits U(s) [loads issued last slot, landed
//     over the barrier] into hs2[s&1]; compute issues its X loads.
//   mini raw barrier (no vmem drain).
//   phase B: compute MFMA+cell+h-stores+own-drain+atomic flag publish (all
//     BEFORE slot barrier -> flag MALL-visible ~0.7us into next slot) ||
//     stage polls U(s+1)'s flag (published last slot -> first-try hit) and
//     issues its 16 fetch loads, which ride the raw slot barrier.
//   raw slot barrier (no vmem drain -> fetch latency spans slots).
// Exposed per-slot cost ~= commit + 2 raw barriers; poll spin and fetch
// latency are off the critical path. Flags: 32 per (bg,hf), value = sum of
// per-wave +1 publishes; consumer target 4*step. 256 blocks = 8bg x 32hg,
// 512 thr = 4 compute + 4 stage waves.
// ---------------------------------------------------------------------------
__global__ __launch_bounds__(512, 1)
void k_lstm(const u16* __restrict__ X1, const u16* __restrict__ Whh,
            const u16* __restrict__ Wcf, const float* __restrict__ bc,
            const u16* __restrict__ Wfcb, const float* __restrict__ bfc,
            u16* __restrict__ hbuf, float* __restrict__ out,
            u32* __restrict__ flags)
{
  __shared__ u16 hs2[2][32 * ZH];   // 2 x 32 KiB, XOR-swizzled half tiles
  const int tid = threadIdx.x;
  const int bg = (int)blockIdx.x >> 5, hg = (int)blockIdx.x & 31;
  const bool isC = (tid < 256);
  const int w = (tid >> 6) & 3, l = tid & 63;
  const int lr = l & 15, lg = l >> 4;
  const int st = tid & 255;
  const int gt = lr >> 2;

  // ---- compute-role persistent state ----
  s8v bwh[16], bwx[4];
  f4v biasv = {0.f, 0.f, 0.f, 0.f};
  float c_reg[2][2][4];   // [hf][m][r] — unroll-static indices (rule 20)
  if (isC){
    const int grow = gt * ZH + hg * 16 + w * 4 + (lr & 3);
    const u16* p = Whh + (size_t)grow * ZH + lg * 8;
    #pragma unroll
    for (int kt = 0; kt < 16; ++kt) bwh[kt] = *(const s8v*)(p + kt * 32);
    const u16* q = Wcf + (size_t)grow * ZEH + lg * 8;
    #pragma unroll
    for (int kt = 0; kt < 4; ++kt) bwx[kt] = *(const s8v*)(q + kt * 32);
    float b = bc[grow];
    biasv[0] = b; biasv[1] = b; biasv[2] = b; biasv[3] = b;
    #pragma unroll
    for (int a = 0; a < 2; ++a){
      #pragma unroll
      for (int m = 0; m < 2; ++m){
        #pragma unroll
        for (int r = 0; r < 4; ++r) c_reg[a][m][r] = 0.f;
      }
    }
  }

  // ---- stage regs: tile to commit at the NEXT slot top. Prologue: U(0) =
  //      h_0[half 0] = zeros ----
  u64 va[8], vb[8];
  #pragma unroll
  for (int i = 0; i < 8; ++i){ va[i] = 0; vb[i] = 0; }
  __syncthreads();

  for (int t = 0; t < ZT; ++t){
    #pragma unroll
    for (int hf = 0; hf < 2; ++hf){
      // ---- phase A: top-commit U(s) | compute issues X loads ----
      s8v ax[2][4];
      if (isC){
        #pragma unroll
        for (int m = 0; m < 2; ++m){
          const u16* xp = X1 + ((size_t)t * ZB + (bg * 64 + hf * 32 + m * 16 + lr)) * ZEH + lg * 8;
          #pragma unroll
          for (int kt = 0; kt < 4; ++kt) ax[m][kt] = *(const s8v*)(xp + kt * 32);
        }
      } else {
        char* dst = (char*)hs2[hf];
        #pragma unroll
        for (int i = 0; i < 8; ++i){
          int byte = (st + i * 256) * 16;
          int swz = byte ^ (((byte >> 5) & 3) << 4);
          *(s8v*)(dst + swz) = pair2v(va[i], vb[i]);
        }
      }
      RAWBAR();   // commit visible; no vmem drain (X loads stay in flight)

      // ---- phase B ----
      if (isC){
        const char* hb = (const char*)hs2[hf];
        f4v accm[2];
        #pragma unroll
        for (int m = 0; m < 2; ++m){
          f4v a0 = biasv;
          f4v a1 = {0.f, 0.f, 0.f, 0.f};
          #pragma unroll
          for (int kt = 0; kt < 8; ++kt){
            int byte = (2 * kt + (lg >> 1)) * 1024 + (m * 16 + lr) * 32 + (lg & 1) * 16;
            byte ^= (((byte >> 5) & 3) << 4);
            s8v av = *(const s8v*)(hb + byte);
            a0 = __builtin_amdgcn_mfma_f32_16x16x32_bf16(av, bwh[kt], a0, 0, 0, 0);
          }
          #pragma unroll
          for (int kt = 8; kt < 16; ++kt){
            int byte = (2 * kt + (lg >> 1)) * 1024 + (m * 16 + lr) * 32 + (lg & 1) * 16;
            byte ^= (((byte >> 5) & 3) << 4);
            s8v av = *(const s8v*)(hb + byte);
            a1 = __builtin_amdgcn_mfma_f32_16x16x32_bf16(av, bwh[kt], a1, 0, 0, 0);
          }
          a0 = __builtin_amdgcn_mfma_f32_16x16x32_bf16(ax[m][0], bwx[0], a0, 0, 0, 0);
          a1 = __builtin_amdgcn_mfma_f32_16x16x32_bf16(ax[m][1], bwx[1], a1, 0, 0, 0);
          a0 = __builtin_amdgcn_mfma_f32_16x16x32_bf16(ax[m][2], bwx[2], a0, 0, 0, 0);
          a1 = __builtin_amdgcn_mfma_f32_16x16x32_bf16(ax[m][3], bwx[3], a1, 0, 0, 0);
          accm[m] = a0 + a1;
        }

        // LSTM cell; h -> global (agent scope)
        u16* hdst = hbuf + qoff2((t + 1) & 1, bg, hf, hg);
        #pragma unroll
        for (int m = 0; m < 2; ++m){
          #pragma unroll
          for (int r = 0; r < 4; ++r){
            float v = accm[m][r];
            float s = (gt == 2) ? 2.f : -1.f;
            float e = __expf(v * s);
            float rc = rcpf(1.f + e);
            float a = (gt == 2) ? (1.f - 2.f * rc) : rc;   // tanh : sigmoid
            float f_ = __shfl_xor(a, 4);
            float g_ = __shfl_xor(a, 8);
            float o_ = __shfl_xor(a, 12);
            float cv = f_ * c_reg[hf][m][r] + a * g_;
            c_reg[hf][m][r] = cv;
            float e2 = __expf(2.f * cv);
            float hv = o_ * (1.f - 2.f * rcpf(1.f + e2));
            u32 bits = f2bf(hv);
            u32 lo = bits | (((u32)__shfl_xor((int)bits, 1)) << 16);
            u32 hi = (u32)__shfl_xor((int)lo, 2);
            if (lr == 0){
              u64 pk = (u64)lo | ((u64)hi << 32);
              __hip_atomic_store((u64*)(hdst + (size_t)(m * 16 + lg * 4 + r) * 16 + w * 4), pk,
                                 __ATOMIC_RELAXED, __HIP_MEMORY_SCOPE_AGENT);
            }
          }
        }
        // per-wave release: drain own h-stores, then atomic flag publish.
        // Flag is MALL-visible ~0.7us after this -> consumers' next-slot
        // poll hits first-try.
        asm volatile("s_waitcnt vmcnt(0)" ::: "memory");
        __builtin_amdgcn_sched_barrier(0);
        if (l == 0)
          __hip_atomic_fetch_add(flags + ((size_t)((bg * 2 + hf) * 32 + hg)) * 16,
                                 1u, __ATOMIC_RELAXED, __HIP_MEMORY_SCOPE_AGENT);
      } else {
        // stage: poll + issue loads for U(s+1) = h_{tfN}[hfN]
        const int hfN = hf ^ 1;
        const int tfN = t + hf;            // hf=0 -> (t,1); hf=1 -> (t+1,0)
        if (!(t == ZT - 1 && hf == 1)){
          if (tfN > 0) qwait(flags, bg * 2 + hfN, (u32)(4 * tfN));
          const u64* src = (const u64*)(hbuf + qoff2(tfN & 1, bg, hfN, 0));
          #pragma unroll
          for (int i = 0; i < 8; ++i){
            int cc = st + i * 256;
            va[i] = aload(src + (size_t)cc * 2);
            vb[i] = aload(src + (size_t)cc * 2 + 1);
          }
        }
      }
      RAWBAR();   // slot end: no vmem drain — fetch loads ride into next top
    }
  }

  // epilogue: hg==0 blocks compute out = h_T @ Wfc^T + bfc (h_T in buf 0)
  if (hg == 0){
    if (tid < 64){
      qwait(flags, bg * 2 + 0, (u32)(4 * ZT));
      qwait(flags, bg * 2 + 1, (u32)(4 * ZT));
    }
    __syncthreads();
    if (isC){
      float ob = (lr < ZNC) ? bfc[lr] : 0.f;
      f4v acc = {ob, ob, ob, ob};
      const u16* wp = Wfcb + (size_t)lr * ZH + lg * 8;
      const int hfE = w >> 1;
      const int ric = (w & 1) * 16 + lr;     // row in 32-row chunk
      #pragma unroll
      for (int kt = 0; kt < 16; ++kt){
        int hgp = 2 * kt + (lg >> 1);
        const u64* hp = (const u64*)(hbuf + qoff2(0, bg, hfE, hgp) + (size_t)ric * 16 + (lg & 1) * 8);
        u64 a0 = aload(hp);
        u64 a1 = aload(hp + 1);
        s8v av = pair2v(a0, a1);
        s8v bv = *(const s8v*)(wp + kt * 32);
        acc = __builtin_amdgcn_mfma_f32_16x16x32_bf16(av, bv, acc, 0, 0, 0);
      }
      if (lr < ZNC){
        #pragma unroll
        for (int r = 0; r < 4; ++r)
          out[(size_t)(bg * 64 + w * 16 + lg * 4 + r) * ZNC + lr] = acc[r];
      }
    }
  }
}

// ---------------------------------------------------------------------------
extern "C" void kernel_launch(void* const* d_in, const int* in_sizes, int n_in,
                              void* d_out, int out_size, void* d_ws, size_t ws_size,
                              hipStream_t stream)
{
  const float* seq  = (const float*)d_in[0];
  const float* W1   = (const float*)d_in[1];
  const float* b1   = (const float*)d_in[2];
  const float* W2   = (const float*)d_in[3];
  const float* b2   = (const float*)d_in[4];
  const float* W_ih = (const float*)d_in[5];
  const float* W_hh = (const float*)d_in[6];
  const float* b_ih = (const float*)d_in[7];
  const float* b_hh = (const float*)d_in[8];
  const float* Wfc  = (const float*)d_in[9];
  const float* bfc  = (const float*)d_in[10];
  float* out = (float*)d_out;

  char* ws = (char*)d_ws;
  size_t off = 0;
  auto alloc = [&](size_t bytes){ void* p = ws + off; off += (bytes + 255) & ~(size_t)255; return p; };
  u16*   Wc    = (u16*)  alloc((size_t)ZG * ZEH * 2);
  float* bc    = (float*)alloc((size_t)ZG * 4);
  u16*   Whh   = (u16*)  alloc((size_t)ZG * ZH * 2);
  u16*   Wfcb  = (u16*)  alloc((size_t)16 * ZH * 2);
  u16*   X1    = (u16*)  alloc((size_t)ZB * ZT * ZEH * 2);
  u16*   hbuf  = (u16*)  alloc((size_t)2 * ZB * ZH * 2);
  u32*   flags = (u32*)  alloc((size_t)8 * 2 * 32 * 16 * 4);  // 64B-padded per (bg,hf,hg)

  hipMemsetAsync(flags, 0, (size_t)8 * 2 * 32 * 16 * 4, stream);
  hipMemsetAsync(hbuf, 0, (size_t)ZB * ZH * 2, stream);      // h_0 = 0 (buffer 0)
  hipMemsetAsync(Wfcb, 0, (size_t)16 * ZH * 2, stream);      // pad rows 8..15 = 0

  hipLaunchKernelGGL(k_fold, dim3(ZG), dim3(128), 0, stream, W_ih, W2, b2, b_ih, b_hh, Wc, bc);
  hipLaunchKernelGGL(k_cvt, dim3((ZG * ZH + 255) / 256), dim3(256), 0, stream, W_hh, Whh, ZG * ZH);
  hipLaunchKernelGGL(k_cvt, dim3((ZNC * ZH + 255) / 256), dim3(256), 0, stream, Wfc, Wfcb, ZNC * ZH);
  hipLaunchKernelGGL(k_enc, dim3(ZB * ZT / 64), dim3(256), 0, stream, seq, W1, b1, X1);
  hipLaunchKernelGGL(k_lstm, dim3(NBLK), dim3(512), 0, stream,
                     X1, Whh, Wc, bc, Wfcb, bfc, hbuf, out, flags);
}

// Round 15
// 2393.232 us; speedup vs baseline: 1.0534x; 1.0534x over previous
//
#include <hip/hip_runtime.h>
#include <cstdint>
#include <cstddef>

#define ZB 512
#define ZT 256
#define ZIN 64
#define ZEH 128
#define ZH 512
#define ZG 2048
#define ZNC 8
#define NBLK 256

typedef __attribute__((ext_vector_type(8))) short s8v;
typedef __attribute__((ext_vector_type(4))) float f4v;
typedef unsigned short u16;
typedef unsigned int u32;
typedef unsigned long long u64;

__device__ __forceinline__ u16 f2bf(float f){
  u32 u = __builtin_bit_cast(u32, f);
  u += 0x7FFFu + ((u >> 16) & 1u);
  return (u16)(u >> 16);
}
__device__ __forceinline__ s8v pair2v(u64 a, u64 b){
  union { u64 q[2]; s8v v; } u; u.q[0] = a; u.q[1] = b; return u.v;
}
// h layout: [buf2][bg8][half2][hg32][32 rows][16 cols] u16; chunk = 1KB/hg
__device__ __forceinline__ size_t qoff2(int buf, int bg, int hf, int hg){
  return ((((size_t)buf * 8 + bg) * 2 + hf) * 32 + hg) * 512;   // u16 elements
}
__device__ __forceinline__ u64 aload(const u64* p){
  return __hip_atomic_load(p, __ATOMIC_RELAXED, __HIP_MEMORY_SCOPE_AGENT);
}
__device__ __forceinline__ float rcpf(float x){
  return __builtin_amdgcn_rcpf(x);   // native 1/x, ~1ulp — gates tolerate it
}

// ---------------------------------------------------------------------------
// Fold: Wc[2048][128] = W_ih @ W2 (bf16), bc[2048] = W_ih@b2 + b_ih + b_hh
// ---------------------------------------------------------------------------
__global__ __launch_bounds__(128)
void k_fold(const float* __restrict__ W_ih, const float* __restrict__ W2,
            const float* __restrict__ b2, const float* __restrict__ b_ih,
            const float* __restrict__ b_hh, u16* __restrict__ Wc,
            float* __restrict__ bc)
{
  const int r = blockIdx.x, c = threadIdx.x;
  const float* wr = W_ih + (size_t)r * ZH;
  float acc = 0.f;
  for (int k = 0; k < ZH; ++k) acc += wr[k] * W2[(size_t)k * ZEH + c];
  Wc[(size_t)r * ZEH + c] = f2bf(acc);
  __shared__ float red[128];
  float p = 0.f;
  for (int k = c; k < ZH; k += 128) p += wr[k] * b2[k];
  red[c] = p; __syncthreads();
  for (int s = 64; s > 0; s >>= 1){ if (c < s) red[c] += red[c + s]; __syncthreads(); }
  if (c == 0) bc[r] = red[0] + b_ih[r] + b_hh[r];
}

__global__ __launch_bounds__(256)
void k_cvt(const float* __restrict__ src, u16* __restrict__ dst, int n)
{
  int i = blockIdx.x * 256 + threadIdx.x;
  if (i < n) dst[i] = f2bf(src[i]);
}

// ---------------------------------------------------------------------------
// Encoder layer 1: X1 (t-major: [T][B][128]) = bf16(LeakyReLU(seq@W1^T+b1))
// ---------------------------------------------------------------------------
__global__ __launch_bounds__(256)
void k_enc(const float* __restrict__ seq, const float* __restrict__ W1,
           const float* __restrict__ b1, u16* __restrict__ X1)
{
  __shared__ float w1s[ZEH * 65];
  __shared__ float sqs[64 * 65];
  const int tid = threadIdx.x;
  const size_t rb = (size_t)blockIdx.x * 64;
  for (int i = tid; i < ZEH * ZIN; i += 256){ int r = i >> 6, c = i & 63; w1s[r * 65 + c] = W1[i]; }
  for (int i = tid; i < 64 * ZIN; i += 256){ int r = i >> 6, c = i & 63; sqs[r * 65 + c] = seq[(rb + r) * ZIN + c]; }
  __syncthreads();
  const int cg = tid & 31, rg = tid >> 5;
  float acc[8][4];
  #pragma unroll
  for (int i = 0; i < 8; ++i){
    #pragma unroll
    for (int j = 0; j < 4; ++j) acc[i][j] = 0.f;
  }
  for (int k = 0; k < ZIN; ++k){
    float wv[4], sv[8];
    #pragma unroll
    for (int j = 0; j < 4; ++j) wv[j] = w1s[(cg * 4 + j) * 65 + k];
    #pragma unroll
    for (int i = 0; i < 8; ++i) sv[i] = sqs[(rg * 8 + i) * 65 + k];
    #pragma unroll
    for (int i = 0; i < 8; ++i){
      #pragma unroll
      for (int j = 0; j < 4; ++j) acc[i][j] += sv[i] * wv[j];
    }
  }
  #pragma unroll
  for (int i = 0; i < 8; ++i){
    ushort4 pk;
    float v0 = acc[i][0] + b1[cg * 4 + 0]; v0 = v0 > 0.f ? v0 : 0.01f * v0;
    float v1 = acc[i][1] + b1[cg * 4 + 1]; v1 = v1 > 0.f ? v1 : 0.01f * v1;
    float v2 = acc[i][2] + b1[cg * 4 + 2]; v2 = v2 > 0.f ? v2 : 0.01f * v2;
    float v3 = acc[i][3] + b1[cg * 4 + 3]; v3 = v3 > 0.f ? v3 : 0.01f * v3;
    pk.x = f2bf(v0); pk.y = f2bf(v1); pk.z = f2bf(v2); pk.w = f2bf(v3);
    int rf = (int)rb + rg * 8 + i;            // flat b*T + t
    int b = rf >> 8, tt = rf & 255;
    *(ushort4*)(X1 + ((size_t)tt * ZB + b) * ZEH + cg * 4) = pk;
  }
}

// ---------------------------------------------------------------------------
// half wait: lane l polls flag[gidx][l&31] (agent scope / MALL); flag value
// is the SUM of per-wave atomic +1 publishes: target = 4 * step.
// ---------------------------------------------------------------------------
__device__ __forceinline__ void qwait(const u32* flags, int gidx, u32 target)
{
  const int l = threadIdx.x & 63;
  const u32* fp = flags + ((size_t)(gidx * 32 + (l & 31))) * 16;
  long long guard = 0;
  for (;;){
    u32 v = __hip_atomic_load(fp, __ATOMIC_RELAXED, __HIP_MEMORY_SCOPE_AGENT);
    if (__ballot(v >= target) == ~0ull) break;
    __builtin_amdgcn_s_sleep(1);
    if (++guard > (1LL << 20)) break;   // fail loud (wrong answer), never hang
  }
}

// ---------------------------------------------------------------------------
// Cooperative LSTM, 2-slot ring (r12 structure, ONE change: early per-wave
// flag publish). 256 blocks = 8 bg x 32 hg, 512 thr = 4 compute + 4 stage:
//   compute: X loads + 40 MFMA + cell + h agent-stores, then OWN vmcnt(0)
//     drain (same cost syncthreads charged in r12, just earlier) + atomic
//     +1 into flag(bg,hf,hg) BEFORE the slot barrier -> flag MALL-visible
//     by slot end -> consumer's first poll HITS (r12's post-barrier tid0
//     publish made every poll miss ~2us, the dominant slot cost).
//   stage (unchanged from r12): poll flag of tile used NEXT slot, fetch
//     32KB to regs, commit XOR-swizzled into the idle LDS buffer — commit
//     overlaps compute (r14's top-commit blocking compute was the mistake).
// Slot end = __syncthreads (full drain; compute already drained -> cheap).
// ---------------------------------------------------------------------------
__global__ __launch_bounds__(512, 1)
void k_lstm(const u16* __restrict__ X1, const u16* __restrict__ Whh,
            const u16* __restrict__ Wcf, const float* __restrict__ bc,
            const u16* __restrict__ Wfcb, const float* __restrict__ bfc,
            u16* __restrict__ hbuf, float* __restrict__ out,
            u32* __restrict__ flags)
{
  __shared__ u16 hs2[2][32 * ZH];   // 2 x 32 KiB, XOR-swizzled half tiles
  const int tid = threadIdx.x;
  const int bg = (int)blockIdx.x >> 5, hg = (int)blockIdx.x & 31;
  const bool isC = (tid < 256);
  const int w = (tid >> 6) & 3, l = tid & 63;
  const int lr = l & 15, lg = l >> 4;
  const int st = tid & 255;
  const int gt = lr >> 2;

  // ---- compute-role persistent state ----
  s8v bwh[16], bwx[4];
  f4v biasv = {0.f, 0.f, 0.f, 0.f};
  float c_reg[2][2][4];   // [hf][m][r] — unroll-static indices (rule 20)
  if (isC){
    const int grow = gt * ZH + hg * 16 + w * 4 + (lr & 3);
    const u16* p = Whh + (size_t)grow * ZH + lg * 8;
    #pragma unroll
    for (int kt = 0; kt < 16; ++kt) bwh[kt] = *(const s8v*)(p + kt * 32);
    const u16* q = Wcf + (size_t)grow * ZEH + lg * 8;
    #pragma unroll
    for (int kt = 0; kt < 4; ++kt) bwx[kt] = *(const s8v*)(q + kt * 32);
    float b = bc[grow];
    biasv[0] = b; biasv[1] = b; biasv[2] = b; biasv[3] = b;
    #pragma unroll
    for (int a = 0; a < 2; ++a){
      #pragma unroll
      for (int m = 0; m < 2; ++m){
        #pragma unroll
        for (int r = 0; r < 4; ++r) c_reg[a][m][r] = 0.f;
      }
    }
  }

  // ---- stage prologue: fetch h_0[half 0] (zeros, buf 0) -> hs2[0] ----
  if (!isC){
    const u64* src = (const u64*)(hbuf + qoff2(0, bg, 0, 0));
    u64 va[8], vb[8];
    #pragma unroll
    for (int i = 0; i < 8; ++i){
      int cc = st + i * 256;
      va[i] = aload(src + (size_t)cc * 2);
      vb[i] = aload(src + (size_t)cc * 2 + 1);
    }
    #pragma unroll
    for (int i = 0; i < 8; ++i){
      int byte = (st + i * 256) * 16;
      int swz = byte ^ (((byte >> 5) & 3) << 4);
      *(s8v*)((char*)hs2[0] + swz) = pair2v(va[i], vb[i]);
    }
  }
  __syncthreads();

  for (int t = 0; t < ZT; ++t){
    #pragma unroll
    for (int hf = 0; hf < 2; ++hf){
      if (isC){
        // X fragments for this slot's 2 m-tiles (t-major; hides under MFMA)
        s8v ax[2][4];
        #pragma unroll
        for (int m = 0; m < 2; ++m){
          const u16* xp = X1 + ((size_t)t * ZB + (bg * 64 + hf * 32 + m * 16 + lr)) * ZEH + lg * 8;
          #pragma unroll
          for (int kt = 0; kt < 4; ++kt) ax[m][kt] = *(const s8v*)(xp + kt * 32);
        }

        const char* hb = (const char*)hs2[hf];
        f4v accm[2];
        #pragma unroll
        for (int m = 0; m < 2; ++m){
          f4v a0 = biasv;
          f4v a1 = {0.f, 0.f, 0.f, 0.f};
          #pragma unroll
          for (int kt = 0; kt < 8; ++kt){
            int byte = (2 * kt + (lg >> 1)) * 1024 + (m * 16 + lr) * 32 + (lg & 1) * 16;
            byte ^= (((byte >> 5) & 3) << 4);
            s8v av = *(const s8v*)(hb + byte);
            a0 = __builtin_amdgcn_mfma_f32_16x16x32_bf16(av, bwh[kt], a0, 0, 0, 0);
          }
          #pragma unroll
          for (int kt = 8; kt < 16; ++kt){
            int byte = (2 * kt + (lg >> 1)) * 1024 + (m * 16 + lr) * 32 + (lg & 1) * 16;
            byte ^= (((byte >> 5) & 3) << 4);
            s8v av = *(const s8v*)(hb + byte);
            a1 = __builtin_amdgcn_mfma_f32_16x16x32_bf16(av, bwh[kt], a1, 0, 0, 0);
          }
          a0 = __builtin_amdgcn_mfma_f32_16x16x32_bf16(ax[m][0], bwx[0], a0, 0, 0, 0);
          a1 = __builtin_amdgcn_mfma_f32_16x16x32_bf16(ax[m][1], bwx[1], a1, 0, 0, 0);
          a0 = __builtin_amdgcn_mfma_f32_16x16x32_bf16(ax[m][2], bwx[2], a0, 0, 0, 0);
          a1 = __builtin_amdgcn_mfma_f32_16x16x32_bf16(ax[m][3], bwx[3], a1, 0, 0, 0);
          accm[m] = a0 + a1;
        }

        // LSTM cell for both m-tiles; h -> global (agent scope)
        u16* hdst = hbuf + qoff2((t + 1) & 1, bg, hf, hg);
        #pragma unroll
        for (int m = 0; m < 2; ++m){
          #pragma unroll
          for (int r = 0; r < 4; ++r){
            float v = accm[m][r];
            float s = (gt == 2) ? 2.f : -1.f;
            float e = __expf(v * s);
            float rc = rcpf(1.f + e);
            float a = (gt == 2) ? (1.f - 2.f * rc) : rc;   // tanh : sigmoid
            float f_ = __shfl_xor(a, 4);
            float g_ = __shfl_xor(a, 8);
            float o_ = __shfl_xor(a, 12);
            float cv = f_ * c_reg[hf][m][r] + a * g_;
            c_reg[hf][m][r] = cv;
            float e2 = __expf(2.f * cv);
            float hv = o_ * (1.f - 2.f * rcpf(1.f + e2));
            u32 bits = f2bf(hv);
            u32 lo = bits | (((u32)__shfl_xor((int)bits, 1)) << 16);
            u32 hi = (u32)__shfl_xor((int)lo, 2);
            if (lr == 0){
              u64 pk = (u64)lo | ((u64)hi << 32);
              __hip_atomic_store((u64*)(hdst + (size_t)(m * 16 + lg * 4 + r) * 16 + w * 4), pk,
                                 __ATOMIC_RELAXED, __HIP_MEMORY_SCOPE_AGENT);
            }
          }
        }
        // EARLY PER-WAVE PUBLISH: drain own h-stores (cost identical to what
        // syncthreads charged in r12), then atomic +1 -> flag visible by the
        // slot boundary -> consumer's first poll hits.
        asm volatile("s_waitcnt vmcnt(0)" ::: "memory");
        __builtin_amdgcn_sched_barrier(0);
        if (l == 0)
          __hip_atomic_fetch_add(flags + ((size_t)((bg * 2 + hf) * 32 + hg)) * 16,
                                 1u, __ATOMIC_RELAXED, __HIP_MEMORY_SCOPE_AGENT);
      } else {
        // stage (r12-identical): tile used NEXT slot = h_{tf}[hfT]
        const int hfT = hf ^ 1;
        const int tf  = t + hf;
        if (tf < ZT || hf == 0){
          if (!(t == 0 && hf == 0))          // h_0[1] needs no wait (zeros)
            qwait(flags, bg * 2 + hfT, (u32)(4 * tf));
          const u64* src = (const u64*)(hbuf + qoff2(tf & 1, bg, hfT, 0));
          u64 va[8], vb[8];
          #pragma unroll
          for (int i = 0; i < 8; ++i){
            int cc = st + i * 256;
            va[i] = aload(src + (size_t)cc * 2);
            vb[i] = aload(src + (size_t)cc * 2 + 1);
          }
          char* dst = (char*)hs2[hf ^ 1];
          #pragma unroll
          for (int i = 0; i < 8; ++i){
            int byte = (st + i * 256) * 16;
            int swz = byte ^ (((byte >> 5) & 3) << 4);
            *(s8v*)(dst + swz) = pair2v(va[i], vb[i]);
          }
        }
      }
      // slot end: full drain + barrier (compute already drained -> cheap)
      __syncthreads();
    }
  }

  // epilogue: hg==0 blocks compute out = h_T @ Wfc^T + bfc (h_T in buf 0)
  if (hg == 0){
    if (tid < 64){
      qwait(flags, bg * 2 + 0, (u32)(4 * ZT));
      qwait(flags, bg * 2 + 1, (u32)(4 * ZT));
    }
    __syncthreads();
    if (isC){
      float ob = (lr < ZNC) ? bfc[lr] : 0.f;
      f4v acc = {ob, ob, ob, ob};
      const u16* wp = Wfcb + (size_t)lr * ZH + lg * 8;
      const int hfE = w >> 1;
      const int ric = (w & 1) * 16 + lr;     // row in 32-row chunk
      #pragma unroll
      for (int kt = 0; kt < 16; ++kt){
        int hgp = 2 * kt + (lg >> 1);
        const u64* hp = (const u64*)(hbuf + qoff2(0, bg, hfE, hgp) + (size_t)ric * 16 + (lg & 1) * 8);
        u64 a0 = aload(hp);
        u64 a1 = aload(hp + 1);
        s8v av = pair2v(a0, a1);
        s8v bv = *(const s8v*)(wp + kt * 32);
        acc = __builtin_amdgcn_mfma_f32_16x16x32_bf16(av, bv, acc, 0, 0, 0);
      }
      if (lr < ZNC){
        #pragma unroll
        for (int r = 0; r < 4; ++r)
          out[(size_t)(bg * 64 + w * 16 + lg * 4 + r) * ZNC + lr] = acc[r];
      }
    }
  }
}

// ---------------------------------------------------------------------------
extern "C" void kernel_launch(void* const* d_in, const int* in_sizes, int n_in,
                              void* d_out, int out_size, void* d_ws, size_t ws_size,
                              hipStream_t stream)
{
  const float* seq  = (const float*)d_in[0];
  const float* W1   = (const float*)d_in[1];
  const float* b1   = (const float*)d_in[2];
  const float* W2   = (const float*)d_in[3];
  const float* b2   = (const float*)d_in[4];
  const float* W_ih = (const float*)d_in[5];
  const float* W_hh = (const float*)d_in[6];
  const float* b_ih = (const float*)d_in[7];
  const float* b_hh = (const float*)d_in[8];
  const float* Wfc  = (const float*)d_in[9];
  const float* bfc  = (const float*)d_in[10];
  float* out = (float*)d_out;

  char* ws = (char*)d_ws;
  size_t off = 0;
  auto alloc = [&](size_t bytes){ void* p = ws + off; off += (bytes + 255) & ~(size_t)255; return p; };
  u16*   Wc    = (u16*)  alloc((size_t)ZG * ZEH * 2);
  float* bc    = (float*)alloc((size_t)ZG * 4);
  u16*   Whh   = (u16*)  alloc((size_t)ZG * ZH * 2);
  u16*   Wfcb  = (u16*)  alloc((size_t)16 * ZH * 2);
  u16*   X1    = (u16*)  alloc((size_t)ZB * ZT * ZEH * 2);
  u16*   hbuf  = (u16*)  alloc((size_t)2 * ZB * ZH * 2);
  u32*   flags = (u32*)  alloc((size_t)8 * 2 * 32 * 16 * 4);  // 64B-padded per (bg,hf,hg)

  hipMemsetAsync(flags, 0, (size_t)8 * 2 * 32 * 16 * 4, stream);
  hipMemsetAsync(hbuf, 0, (size_t)ZB * ZH * 2, stream);      // h_0 = 0 (buffer 0)
  hipMemsetAsync(Wfcb, 0, (size_t)16 * ZH * 2, stream);      // pad rows 8..15 = 0

  hipLaunchKernelGGL(k_fold, dim3(ZG), dim3(128), 0, stream, W_ih, W2, b2, b_ih, b_hh, Wc, bc);
  hipLaunchKernelGGL(k_cvt, dim3((ZG * ZH + 255) / 256), dim3(256), 0, stream, W_hh, Whh, ZG * ZH);
  hipLaunchKernelGGL(k_cvt, dim3((ZNC * ZH + 255) / 256), dim3(256), 0, stream, Wfc, Wfcb, ZNC * ZH);
  hipLaunchKernelGGL(k_enc, dim3(ZB * ZT / 64), dim3(256), 0, stream, seq, W1, b1, X1);
  hipLaunchKernelGGL(k_lstm, dim3(NBLK), dim3(512), 0, stream,
                     X1, Whh, Wc, bc, Wfcb, bfc, hbuf, out, flags);
}

// Round 16
// 2230.694 us; speedup vs baseline: 1.1302x; 1.0729x over previous
//
#include <hip/hip_runtime.h>
#include <cstdint>
#include <cstddef>

#define ZB 512
#define ZT 256
#define ZIN 64
#define ZEH 128
#define ZH 512
#define ZG 2048
#define ZNC 8
#define NBLK 256

typedef __attribute__((ext_vector_type(8))) short s8v;
typedef __attribute__((ext_vector_type(4))) float f4v;
typedef unsigned short u16;
typedef unsigned int u32;
typedef unsigned long long u64;

__device__ __forceinline__ u16 f2bf(float f){
  u32 u = __builtin_bit_cast(u32, f);
  u += 0x7FFFu + ((u >> 16) & 1u);
  return (u16)(u >> 16);
}
__device__ __forceinline__ s8v pair2v(u64 a, u64 b){
  union { u64 q[2]; s8v v; } u; u.q[0] = a; u.q[1] = b; return u.v;
}
// h layout: [buf2][bg16][half2][chunk32][16 rows][16 cols] u16
// chunk = hidden-16-col group (hg*2+sub); per-chunk = 512B contiguous
__device__ __forceinline__ size_t qoff3(int buf, int bg, int hf, int ch){
  return ((((size_t)buf * 16 + bg) * 2 + hf) * 32 + ch) * 256;   // u16 elems
}
__device__ __forceinline__ u64 aload(const u64* p){
  return __hip_atomic_load(p, __ATOMIC_RELAXED, __HIP_MEMORY_SCOPE_AGENT);
}
__device__ __forceinline__ float rcpf(float x){
  return __builtin_amdgcn_rcpf(x);   // native 1/x, ~1ulp — gates tolerate it
}

// ---------------------------------------------------------------------------
// Fold: Wc[2048][128] = W_ih @ W2 (bf16), bc[2048] = W_ih@b2 + b_ih + b_hh
// ---------------------------------------------------------------------------
__global__ __launch_bounds__(128)
void k_fold(const float* __restrict__ W_ih, const float* __restrict__ W2,
            const float* __restrict__ b2, const float* __restrict__ b_ih,
            const float* __restrict__ b_hh, u16* __restrict__ Wc,
            float* __restrict__ bc)
{
  const int r = blockIdx.x, c = threadIdx.x;
  const float* wr = W_ih + (size_t)r * ZH;
  float acc = 0.f;
  for (int k = 0; k < ZH; ++k) acc += wr[k] * W2[(size_t)k * ZEH + c];
  Wc[(size_t)r * ZEH + c] = f2bf(acc);
  __shared__ float red[128];
  float p = 0.f;
  for (int k = c; k < ZH; k += 128) p += wr[k] * b2[k];
  red[c] = p; __syncthreads();
  for (int s = 64; s > 0; s >>= 1){ if (c < s) red[c] += red[c + s]; __syncthreads(); }
  if (c == 0) bc[r] = red[0] + b_ih[r] + b_hh[r];
}

__global__ __launch_bounds__(256)
void k_cvt(const float* __restrict__ src, u16* __restrict__ dst, int n)
{
  int i = blockIdx.x * 256 + threadIdx.x;
  if (i < n) dst[i] = f2bf(src[i]);
}

// ---------------------------------------------------------------------------
// Encoder layer 1: X1 (t-major: [T][B][128]) = bf16(LeakyReLU(seq@W1^T+b1))
// ---------------------------------------------------------------------------
__global__ __launch_bounds__(256)
void k_enc(const float* __restrict__ seq, const float* __restrict__ W1,
           const float* __restrict__ b1, u16* __restrict__ X1)
{
  __shared__ float w1s[ZEH * 65];
  __shared__ float sqs[64 * 65];
  const int tid = threadIdx.x;
  const size_t rb = (size_t)blockIdx.x * 64;
  for (int i = tid; i < ZEH * ZIN; i += 256){ int r = i >> 6, c = i & 63; w1s[r * 65 + c] = W1[i]; }
  for (int i = tid; i < 64 * ZIN; i += 256){ int r = i >> 6, c = i & 63; sqs[r * 65 + c] = seq[(rb + r) * ZIN + c]; }
  __syncthreads();
  const int cg = tid & 31, rg = tid >> 5;
  float acc[8][4];
  #pragma unroll
  for (int i = 0; i < 8; ++i){
    #pragma unroll
    for (int j = 0; j < 4; ++j) acc[i][j] = 0.f;
  }
  for (int k = 0; k < ZIN; ++k){
    float wv[4], sv[8];
    #pragma unroll
    for (int j = 0; j < 4; ++j) wv[j] = w1s[(cg * 4 + j) * 65 + k];
    #pragma unroll
    for (int i = 0; i < 8; ++i) sv[i] = sqs[(rg * 8 + i) * 65 + k];
    #pragma unroll
    for (int i = 0; i < 8; ++i){
      #pragma unroll
      for (int j = 0; j < 4; ++j) acc[i][j] += sv[i] * wv[j];
    }
  }
  #pragma unroll
  for (int i = 0; i < 8; ++i){
    ushort4 pk;
    float v0 = acc[i][0] + b1[cg * 4 + 0]; v0 = v0 > 0.f ? v0 : 0.01f * v0;
    float v1 = acc[i][1] + b1[cg * 4 + 1]; v1 = v1 > 0.f ? v1 : 0.01f * v1;
    float v2 = acc[i][2] + b1[cg * 4 + 2]; v2 = v2 > 0.f ? v2 : 0.01f * v2;
    float v3 = acc[i][3] + b1[cg * 4 + 3]; v3 = v3 > 0.f ? v3 : 0.01f * v3;
    pk.x = f2bf(v0); pk.y = f2bf(v1); pk.z = f2bf(v2); pk.w = f2bf(v3);
    int rf = (int)rb + rg * 8 + i;            // flat b*T + t
    int b = rf >> 8, tt = rf & 255;
    *(ushort4*)(X1 + ((size_t)tt * ZB + b) * ZEH + cg * 4) = pk;
  }
}

// ---------------------------------------------------------------------------
// half wait: lane l polls flag[gidx][l&15] (agent scope / MALL).
// gidx = bg*2+hf; 16 flags (one per hg block), 64B-padded; value = step done.
// ---------------------------------------------------------------------------
__device__ __forceinline__ void qwait(const u32* flags, int gidx, u32 target)
{
  const int l = threadIdx.x & 63;
  const u32* fp = flags + ((size_t)(gidx * 16 + (l & 15))) * 16;
  long long guard = 0;
  for (;;){
    u32 v = __hip_atomic_load(fp, __ATOMIC_RELAXED, __HIP_MEMORY_SCOPE_AGENT);
    if (__ballot(v >= target) == ~0ull) break;
    __builtin_amdgcn_s_sleep(1);
    if (++guard > (1LL << 20)) break;   // fail loud (wrong answer), never hang
  }
}

// ---------------------------------------------------------------------------
// Cooperative LSTM, r12 slot structure & publish protocol, 2x finer grid:
// 256 blocks = 16 bg (32 batch rows) x 16 hg (32 hidden cols), 1024 thr =
// 8 compute + 8 stage waves. Slot = 16-row half-tile (1 m-tile, 20 MFMA per
// compute wave — half of r12's per-wave work at the same slot count; the
// measured fixed cost F~1.45us/slot amortizes over 2x block parallelism).
//   compute wave w: owns gate rows gt*512 + hg*32 + w*4 + (lr&3); X loads +
//     20 MFMA + cell + h agent-stores.
//   stage: poll flag of tile used NEXT slot (r12 protocol), fetch 16KB to
//     regs, commit XOR-swizzled into idle LDS buffer (overlaps compute).
// Slot end = __syncthreads; tid0 publishes flag AFTER barrier (r12-exact —
// r13/14/15 all proved touching this regresses).
// ---------------------------------------------------------------------------
__global__ __launch_bounds__(1024, 1)
void k_lstm(const u16* __restrict__ X1, const u16* __restrict__ Whh,
            const u16* __restrict__ Wcf, const float* __restrict__ bc,
            const u16* __restrict__ Wfcb, const float* __restrict__ bfc,
            u16* __restrict__ hbuf, float* __restrict__ out,
            u32* __restrict__ flags)
{
  __shared__ u16 hs2[2][16 * ZH];   // 2 x 16 KiB, XOR-swizzled half tiles
  const int tid = threadIdx.x;
  const int bg = (int)blockIdx.x >> 4, hg = (int)blockIdx.x & 15;
  const bool isC = (tid < 512);
  const int w = (tid >> 6) & 7, l = tid & 63;
  const int lr = l & 15, lg = l >> 4;
  const int st = tid & 511;
  const int gt = lr >> 2;

  // ---- compute-role persistent state ----
  s8v bwh[16], bwx[4];
  f4v biasv = {0.f, 0.f, 0.f, 0.f};
  float c_reg[2][4];   // [hf][r] — unroll-static indices (rule 20)
  if (isC){
    const int grow = gt * ZH + hg * 32 + w * 4 + (lr & 3);
    const u16* p = Whh + (size_t)grow * ZH + lg * 8;
    #pragma unroll
    for (int kt = 0; kt < 16; ++kt) bwh[kt] = *(const s8v*)(p + kt * 32);
    const u16* q = Wcf + (size_t)grow * ZEH + lg * 8;
    #pragma unroll
    for (int kt = 0; kt < 4; ++kt) bwx[kt] = *(const s8v*)(q + kt * 32);
    float b = bc[grow];
    biasv[0] = b; biasv[1] = b; biasv[2] = b; biasv[3] = b;
    #pragma unroll
    for (int a = 0; a < 2; ++a){
      #pragma unroll
      for (int r = 0; r < 4; ++r) c_reg[a][r] = 0.f;
    }
  }

  // ---- stage prologue: fetch h_0[half 0] (zeros, buf 0) -> hs2[0] ----
  if (!isC){
    const u64* src = (const u64*)(hbuf + qoff3(0, bg, 0, 0));
    u64 va[2], vb[2];
    #pragma unroll
    for (int i = 0; i < 2; ++i){
      int cc = st + i * 512;
      va[i] = aload(src + (size_t)cc * 2);
      vb[i] = aload(src + (size_t)cc * 2 + 1);
    }
    #pragma unroll
    for (int i = 0; i < 2; ++i){
      int byte = (st + i * 512) * 16;
      int swz = byte ^ (((byte >> 5) & 3) << 4);
      *(s8v*)((char*)hs2[0] + swz) = pair2v(va[i], vb[i]);
    }
  }
  __syncthreads();

  for (int t = 0; t < ZT; ++t){
    #pragma unroll
    for (int hf = 0; hf < 2; ++hf){
      if (isC){
        // X fragments for this slot's m-tile (t-major; hides under MFMA)
        s8v ax[4];
        {
          const u16* xp = X1 + ((size_t)t * ZB + (bg * 32 + hf * 16 + lr)) * ZEH + lg * 8;
          #pragma unroll
          for (int kt = 0; kt < 4; ++kt) ax[kt] = *(const s8v*)(xp + kt * 32);
        }

        const char* hb = (const char*)hs2[hf];
        f4v a0 = biasv;
        f4v a1 = {0.f, 0.f, 0.f, 0.f};
        #pragma unroll
        for (int kt = 0; kt < 8; ++kt){
          int byte = (2 * kt + (lg >> 1)) * 512 + lr * 32 + (lg & 1) * 16;
          byte ^= ((lr & 3) << 4);
          s8v av = *(const s8v*)(hb + byte);
          a0 = __builtin_amdgcn_mfma_f32_16x16x32_bf16(av, bwh[kt], a0, 0, 0, 0);
        }
        #pragma unroll
        for (int kt = 8; kt < 16; ++kt){
          int byte = (2 * kt + (lg >> 1)) * 512 + lr * 32 + (lg & 1) * 16;
          byte ^= ((lr & 3) << 4);
          s8v av = *(const s8v*)(hb + byte);
          a1 = __builtin_amdgcn_mfma_f32_16x16x32_bf16(av, bwh[kt], a1, 0, 0, 0);
        }
        a0 = __builtin_amdgcn_mfma_f32_16x16x32_bf16(ax[0], bwx[0], a0, 0, 0, 0);
        a1 = __builtin_amdgcn_mfma_f32_16x16x32_bf16(ax[1], bwx[1], a1, 0, 0, 0);
        a0 = __builtin_amdgcn_mfma_f32_16x16x32_bf16(ax[2], bwx[2], a0, 0, 0, 0);
        a1 = __builtin_amdgcn_mfma_f32_16x16x32_bf16(ax[3], bwx[3], a1, 0, 0, 0);
        f4v acc = a0 + a1;

        // LSTM cell; h -> global (agent scope). Wave w -> chunk hg*2+(w>>2),
        // cols (w&3)*4..+3 within the chunk.
        u16* hdst = hbuf + qoff3((t + 1) & 1, bg, hf, hg * 2 + (w >> 2));
        #pragma unroll
        for (int r = 0; r < 4; ++r){
          float v = acc[r];
          float s = (gt == 2) ? 2.f : -1.f;
          float e = __expf(v * s);
          float rc = rcpf(1.f + e);
          float a = (gt == 2) ? (1.f - 2.f * rc) : rc;   // tanh : sigmoid
          float f_ = __shfl_xor(a, 4);
          float g_ = __shfl_xor(a, 8);
          float o_ = __shfl_xor(a, 12);
          float cv = f_ * c_reg[hf][r] + a * g_;
          c_reg[hf][r] = cv;
          float e2 = __expf(2.f * cv);
          float hv = o_ * (1.f - 2.f * rcpf(1.f + e2));
          u32 bits = f2bf(hv);
          u32 lo = bits | (((u32)__shfl_xor((int)bits, 1)) << 16);
          u32 hi = (u32)__shfl_xor((int)lo, 2);
          if (lr == 0){
            u64 pk = (u64)lo | ((u64)hi << 32);
            __hip_atomic_store((u64*)(hdst + (size_t)(lg * 4 + r) * 16 + (w & 3) * 4), pk,
                               __ATOMIC_RELAXED, __HIP_MEMORY_SCOPE_AGENT);
          }
        }
      } else {
        // stage (r12-identical): tile used NEXT slot = h_{tf}[hfT]
        const int hfT = hf ^ 1;
        const int tf  = t + hf;
        if (tf < ZT || hf == 0){
          if (!(t == 0 && hf == 0))          // h_0[1] needs no wait (zeros)
            qwait(flags, bg * 2 + hfT, (u32)tf);
          const u64* src = (const u64*)(hbuf + qoff3(tf & 1, bg, hfT, 0));
          u64 va[2], vb[2];
          #pragma unroll
          for (int i = 0; i < 2; ++i){
            int cc = st + i * 512;
            va[i] = aload(src + (size_t)cc * 2);
            vb[i] = aload(src + (size_t)cc * 2 + 1);
          }
          char* dst = (char*)hs2[hf ^ 1];
          #pragma unroll
          for (int i = 0; i < 2; ++i){
            int byte = (st + i * 512) * 16;
            int swz = byte ^ (((byte >> 5) & 3) << 4);
            *(s8v*)(dst + swz) = pair2v(va[i], vb[i]);
          }
        }
      }
      // slot end: full drain (syncthreads) then publish this half's flag
      __syncthreads();
      if (tid == 0)
        __hip_atomic_store(flags + ((size_t)((bg * 2 + hf) * 16 + hg)) * 16,
                           (u32)(t + 1), __ATOMIC_RELAXED, __HIP_MEMORY_SCOPE_AGENT);
    }
  }

  // epilogue: hg==0 blocks compute out = h_T @ Wfc^T + bfc (h_T in buf 0)
  if (hg == 0){
    if (tid < 64){
      qwait(flags, bg * 2 + 0, (u32)ZT);
      qwait(flags, bg * 2 + 1, (u32)ZT);
    }
    __syncthreads();
    if (isC && w < 2){        // 2 waves x 16 rows = this bg's 32 batch rows
      float ob = (lr < ZNC) ? bfc[lr] : 0.f;
      f4v acc = {ob, ob, ob, ob};
      const u16* wp = Wfcb + (size_t)lr * ZH + lg * 8;
      #pragma unroll
      for (int kt = 0; kt < 16; ++kt){
        int ch = 2 * kt + (lg >> 1);
        const u64* hp = (const u64*)(hbuf + qoff3(0, bg, w, ch)) + lr * 4 + (lg & 1) * 2;
        u64 a0 = aload(hp);
        u64 a1 = aload(hp + 1);
        s8v av = pair2v(a0, a1);
        s8v bv = *(const s8v*)(wp + kt * 32);
        acc = __builtin_amdgcn_mfma_f32_16x16x32_bf16(av, bv, acc, 0, 0, 0);
      }
      if (lr < ZNC){
        #pragma unroll
        for (int r = 0; r < 4; ++r)
          out[(size_t)(bg * 32 + w * 16 + lg * 4 + r) * ZNC + lr] = acc[r];
      }
    }
  }
}

// ---------------------------------------------------------------------------
extern "C" void kernel_launch(void* const* d_in, const int* in_sizes, int n_in,
                              void* d_out, int out_size, void* d_ws, size_t ws_size,
                              hipStream_t stream)
{
  const float* seq  = (const float*)d_in[0];
  const float* W1   = (const float*)d_in[1];
  const float* b1   = (const float*)d_in[2];
  const float* W2   = (const float*)d_in[3];
  const float* b2   = (const float*)d_in[4];
  const float* W_ih = (const float*)d_in[5];
  const float* W_hh = (const float*)d_in[6];
  const float* b_ih = (const float*)d_in[7];
  const float* b_hh = (const float*)d_in[8];
  const float* Wfc  = (const float*)d_in[9];
  const float* bfc  = (const float*)d_in[10];
  float* out = (float*)d_out;

  char* ws = (char*)d_ws;
  size_t off = 0;
  auto alloc = [&](size_t bytes){ void* p = ws + off; off += (bytes + 255) & ~(size_t)255; return p; };
  u16*   Wc    = (u16*)  alloc((size_t)ZG * ZEH * 2);
  float* bc    = (float*)alloc((size_t)ZG * 4);
  u16*   Whh   = (u16*)  alloc((size_t)ZG * ZH * 2);
  u16*   Wfcb  = (u16*)  alloc((size_t)16 * ZH * 2);
  u16*   X1    = (u16*)  alloc((size_t)ZB * ZT * ZEH * 2);
  u16*   hbuf  = (u16*)  alloc((size_t)2 * ZB * ZH * 2);
  u32*   flags = (u32*)  alloc((size_t)16 * 2 * 16 * 64);   // 64B-padded per (bg,hf,hg)

  hipMemsetAsync(flags, 0, (size_t)16 * 2 * 16 * 64, stream);
  hipMemsetAsync(hbuf, 0, (size_t)ZB * ZH * 2, stream);      // h_0 = 0 (buffer 0)
  hipMemsetAsync(Wfcb, 0, (size_t)16 * ZH * 2, stream);      // pad rows 8..15 = 0

  hipLaunchKernelGGL(k_fold, dim3(ZG), dim3(128), 0, stream, W_ih, W2, b2, b_ih, b_hh, Wc, bc);
  hipLaunchKernelGGL(k_cvt, dim3((ZG * ZH + 255) / 256), dim3(256), 0, stream, W_hh, Whh, ZG * ZH);
  hipLaunchKernelGGL(k_cvt, dim3((ZNC * ZH + 255) / 256), dim3(256), 0, stream, Wfc, Wfcb, ZNC * ZH);
  hipLaunchKernelGGL(k_enc, dim3(ZB * ZT / 64), dim3(256), 0, stream, seq, W1, b1, X1);
  hipLaunchKernelGGL(k_lstm, dim3(NBLK), dim3(1024), 0, stream,
                     X1, Whh, Wc, bc, Wfcb, bfc, hbuf, out, flags);
}

// Round 17
// 1752.175 us; speedup vs baseline: 1.4389x; 1.2731x over previous
//
#include <hip/hip_runtime.h>
#include <cstdint>
#include <cstddef>

#define ZB 512
#define ZT 256
#define ZIN 64
#define ZEH 128
#define ZH 512
#define ZG 2048
#define ZNC 8
#define NBLK 256

typedef __attribute__((ext_vector_type(8))) short s8v;
typedef __attribute__((ext_vector_type(4))) float f4v;
typedef unsigned short u16;
typedef unsigned int u32;
typedef unsigned long long u64;

__device__ __forceinline__ u16 f2bf(float f){
  u32 u = __builtin_bit_cast(u32, f);
  u += 0x7FFFu + ((u >> 16) & 1u);
  return (u16)(u >> 16);
}
__device__ __forceinline__ s8v pair2v(u64 a, u64 b){
  union { u64 q[2]; s8v v; } u; u.q[0] = a; u.q[1] = b; return u.v;
}
// h layout: [buf2][bg8][half2][hg32][32 rows][16 cols] u16; chunk = 1KB/hg
__device__ __forceinline__ size_t qoff2(int buf, int bg, int hf, int hg){
  return ((((size_t)buf * 8 + bg) * 2 + hf) * 32 + hg) * 512;   // u16 elements
}
__device__ __forceinline__ u64 aload(const u64* p){
  return __hip_atomic_load(p, __ATOMIC_RELAXED, __HIP_MEMORY_SCOPE_AGENT);
}

// ---------------------------------------------------------------------------
// Fold: Wc[2048][128] = W_ih @ W2 (bf16), bc[2048] = W_ih@b2 + b_ih + b_hh
// ---------------------------------------------------------------------------
__global__ __launch_bounds__(128)
void k_fold(const float* __restrict__ W_ih, const float* __restrict__ W2,
            const float* __restrict__ b2, const float* __restrict__ b_ih,
            const float* __restrict__ b_hh, u16* __restrict__ Wc,
            float* __restrict__ bc)
{
  const int r = blockIdx.x, c = threadIdx.x;
  const float* wr = W_ih + (size_t)r * ZH;
  float acc = 0.f;
  for (int k = 0; k < ZH; ++k) acc += wr[k] * W2[(size_t)k * ZEH + c];
  Wc[(size_t)r * ZEH + c] = f2bf(acc);
  __shared__ float red[128];
  float p = 0.f;
  for (int k = c; k < ZH; k += 128) p += wr[k] * b2[k];
  red[c] = p; __syncthreads();
  for (int s = 64; s > 0; s >>= 1){ if (c < s) red[c] += red[c + s]; __syncthreads(); }
  if (c == 0) bc[r] = red[0] + b_ih[r] + b_hh[r];
}

__global__ __launch_bounds__(256)
void k_cvt(const float* __restrict__ src, u16* __restrict__ dst, int n)
{
  int i = blockIdx.x * 256 + threadIdx.x;
  if (i < n) dst[i] = f2bf(src[i]);
}

// ---------------------------------------------------------------------------
// Encoder layer 1: X1 (t-major: [T][B][128]) = bf16(LeakyReLU(seq@W1^T+b1))
// ---------------------------------------------------------------------------
__global__ __launch_bounds__(256)
void k_enc(const float* __restrict__ seq, const float* __restrict__ W1,
           const float* __restrict__ b1, u16* __restrict__ X1)
{
  __shared__ float w1s[ZEH * 65];
  __shared__ float sqs[64 * 65];
  const int tid = threadIdx.x;
  const size_t rb = (size_t)blockIdx.x * 64;
  for (int i = tid; i < ZEH * ZIN; i += 256){ int r = i >> 6, c = i & 63; w1s[r * 65 + c] = W1[i]; }
  for (int i = tid; i < 64 * ZIN; i += 256){ int r = i >> 6, c = i & 63; sqs[r * 65 + c] = seq[(rb + r) * ZIN + c]; }
  __syncthreads();
  const int cg = tid & 31, rg = tid >> 5;
  float acc[8][4];
  #pragma unroll
  for (int i = 0; i < 8; ++i){
    #pragma unroll
    for (int j = 0; j < 4; ++j) acc[i][j] = 0.f;
  }
  for (int k = 0; k < ZIN; ++k){
    float wv[4], sv[8];
    #pragma unroll
    for (int j = 0; j < 4; ++j) wv[j] = w1s[(cg * 4 + j) * 65 + k];
    #pragma unroll
    for (int i = 0; i < 8; ++i) sv[i] = sqs[(rg * 8 + i) * 65 + k];
    #pragma unroll
    for (int i = 0; i < 8; ++i){
      #pragma unroll
      for (int j = 0; j < 4; ++j) acc[i][j] += sv[i] * wv[j];
    }
  }
  #pragma unroll
  for (int i = 0; i < 8; ++i){
    ushort4 pk;
    float v0 = acc[i][0] + b1[cg * 4 + 0]; v0 = v0 > 0.f ? v0 : 0.01f * v0;
    float v1 = acc[i][1] + b1[cg * 4 + 1]; v1 = v1 > 0.f ? v1 : 0.01f * v1;
    float v2 = acc[i][2] + b1[cg * 4 + 2]; v2 = v2 > 0.f ? v2 : 0.01f * v2;
    float v3 = acc[i][3] + b1[cg * 4 + 3]; v3 = v3 > 0.f ? v3 : 0.01f * v3;
    pk.x = f2bf(v0); pk.y = f2bf(v1); pk.z = f2bf(v2); pk.w = f2bf(v3);
    int rf = (int)rb + rg * 8 + i;            // flat b*T + t
    int b = rf >> 8, tt = rf & 255;
    *(ushort4*)(X1 + ((size_t)tt * ZB + b) * ZEH + cg * 4) = pk;
  }
}

// ---------------------------------------------------------------------------
// half wait: lane l polls flag[gidx][l&31] (agent scope / MALL).
// gidx = bg*2 + hf. Flags 64B-padded.
// ---------------------------------------------------------------------------
__device__ __forceinline__ void qwait(const u32* flags, int gidx, u32 target)
{
  const int l = threadIdx.x & 63;
  const u32* fp = flags + ((size_t)(gidx * 32 + (l & 31))) * 16;
  long long guard = 0;
  for (;;){
    u32 v = __hip_atomic_load(fp, __ATOMIC_RELAXED, __HIP_MEMORY_SCOPE_AGENT);
    if (__ballot(v >= target) == ~0ull) break;
    __builtin_amdgcn_s_sleep(1);
    if (++guard > (1LL << 20)) break;   // fail loud (wrong answer), never hang
  }
}

// ---------------------------------------------------------------------------
// Cooperative LSTM, 2-slot ring (32-row half-tiles): 512 slots total — the
// per-slot fixed cost (~1.4us, invariant across structures r5/r6/r7/r11) is
// amortized over 2x the work vs a 4-slot ring. BEST-MEASURED VARIANT (r12,
// 1758.9us): syncthreads slot ends (implicit full drain), tid0 publish AFTER
// the barrier, qwait poll in stage waves. Rounds 13-16 proved every
// perturbation (early publish, flag prefetch, top-commit, finer grid)
// regresses: the protocol's speed comes from compiler cross-slot pipelining,
// which inserted fences/atomics destroy.
// 256 blocks = 8 bg x 32 hg, 512 thr:
//   waves 0-3 compute: W_hh/Wc slices in regs; per slot 2 m-tiles (40 MFMA),
//     cell, h agent-stores.
//   waves 4-7 stage: poll flag (published end of prev slot), fetch 32KB half
//     tile (MALL), commit swizzled into the idle LDS buffer — all in-slot;
//     the poll+fetch RTTs overlap compute's ~2us of work.
// Slot (t,hf): parity hf; uses h_t[half hf] from hs2[hf]; produces
// h_{t+1}[hf]; stage fetches the half used at slot+1 into hs2[hf^1].
// ---------------------------------------------------------------------------
__global__ __launch_bounds__(512, 1)
void k_lstm(const u16* __restrict__ X1, const u16* __restrict__ Whh,
            const u16* __restrict__ Wcf, const float* __restrict__ bc,
            const u16* __restrict__ Wfcb, const float* __restrict__ bfc,
            u16* __restrict__ hbuf, float* __restrict__ out,
            u32* __restrict__ flags)
{
  __shared__ u16 hs2[2][32 * ZH];   // 2 x 32 KiB, XOR-swizzled half tiles
  const int tid = threadIdx.x;
  const int bg = (int)blockIdx.x >> 5, hg = (int)blockIdx.x & 31;
  const bool isC = (tid < 256);
  const int w = (tid >> 6) & 3, l = tid & 63;
  const int lr = l & 15, lg = l >> 4;
  const int st = tid & 255;
  const int gt = lr >> 2;

  // ---- compute-role persistent state ----
  s8v bwh[16], bwx[4];
  f4v biasv = {0.f, 0.f, 0.f, 0.f};
  float c_reg[2][2][4];   // [hf][m][r] — unroll-static indices (rule 20)
  if (isC){
    const int grow = gt * ZH + hg * 16 + w * 4 + (lr & 3);
    const u16* p = Whh + (size_t)grow * ZH + lg * 8;
    #pragma unroll
    for (int kt = 0; kt < 16; ++kt) bwh[kt] = *(const s8v*)(p + kt * 32);
    const u16* q = Wcf + (size_t)grow * ZEH + lg * 8;
    #pragma unroll
    for (int kt = 0; kt < 4; ++kt) bwx[kt] = *(const s8v*)(q + kt * 32);
    float b = bc[grow];
    biasv[0] = b; biasv[1] = b; biasv[2] = b; biasv[3] = b;
    #pragma unroll
    for (int a = 0; a < 2; ++a){
      #pragma unroll
      for (int m = 0; m < 2; ++m){
        #pragma unroll
        for (int r = 0; r < 4; ++r) c_reg[a][m][r] = 0.f;
      }
    }
  }

  // ---- stage prologue: fetch h_0[half 0] (zeros, buf 0) -> hs2[0] ----
  if (!isC){
    const u64* src = (const u64*)(hbuf + qoff2(0, bg, 0, 0));
    u64 va[8], vb[8];
    #pragma unroll
    for (int i = 0; i < 8; ++i){
      int cc = st + i * 256;
      va[i] = aload(src + (size_t)cc * 2);
      vb[i] = aload(src + (size_t)cc * 2 + 1);
    }
    #pragma unroll
    for (int i = 0; i < 8; ++i){
      int byte = (st + i * 256) * 16;
      int swz = byte ^ (((byte >> 5) & 3) << 4);
      *(s8v*)((char*)hs2[0] + swz) = pair2v(va[i], vb[i]);
    }
  }
  __syncthreads();

  u32* flbase = flags + ((size_t)(bg * 64 + hg)) * 16;   // + hf*512 selects half

  for (int t = 0; t < ZT; ++t){
    #pragma unroll
    for (int hf = 0; hf < 2; ++hf){
      if (isC){
        // X fragments for this slot's 2 m-tiles (t-major; hides under MFMA)
        s8v ax[2][4];
        #pragma unroll
        for (int m = 0; m < 2; ++m){
          const u16* xp = X1 + ((size_t)t * ZB + (bg * 64 + hf * 32 + m * 16 + lr)) * ZEH + lg * 8;
          #pragma unroll
          for (int kt = 0; kt < 4; ++kt) ax[m][kt] = *(const s8v*)(xp + kt * 32);
        }

        const char* hb = (const char*)hs2[hf];
        f4v accm[2];
        #pragma unroll
        for (int m = 0; m < 2; ++m){
          f4v a0 = biasv;
          f4v a1 = {0.f, 0.f, 0.f, 0.f};
          #pragma unroll
          for (int kt = 0; kt < 8; ++kt){
            int byte = (2 * kt + (lg >> 1)) * 1024 + (m * 16 + lr) * 32 + (lg & 1) * 16;
            byte ^= (((byte >> 5) & 3) << 4);
            s8v av = *(const s8v*)(hb + byte);
            a0 = __builtin_amdgcn_mfma_f32_16x16x32_bf16(av, bwh[kt], a0, 0, 0, 0);
          }
          #pragma unroll
          for (int kt = 8; kt < 16; ++kt){
            int byte = (2 * kt + (lg >> 1)) * 1024 + (m * 16 + lr) * 32 + (lg & 1) * 16;
            byte ^= (((byte >> 5) & 3) << 4);
            s8v av = *(const s8v*)(hb + byte);
            a1 = __builtin_amdgcn_mfma_f32_16x16x32_bf16(av, bwh[kt], a1, 0, 0, 0);
          }
          a0 = __builtin_amdgcn_mfma_f32_16x16x32_bf16(ax[m][0], bwx[0], a0, 0, 0, 0);
          a1 = __builtin_amdgcn_mfma_f32_16x16x32_bf16(ax[m][1], bwx[1], a1, 0, 0, 0);
          a0 = __builtin_amdgcn_mfma_f32_16x16x32_bf16(ax[m][2], bwx[2], a0, 0, 0, 0);
          a1 = __builtin_amdgcn_mfma_f32_16x16x32_bf16(ax[m][3], bwx[3], a1, 0, 0, 0);
          accm[m] = a0 + a1;
        }

        // LSTM cell for both m-tiles; h -> global (agent scope)
        u16* hdst = hbuf + qoff2((t + 1) & 1, bg, hf, hg);
        #pragma unroll
        for (int m = 0; m < 2; ++m){
          #pragma unroll
          for (int r = 0; r < 4; ++r){
            float v = accm[m][r];
            float s = (gt == 2) ? 2.f : -1.f;
            float e = __expf(v * s);
            float rc = 1.f / (1.f + e);
            float a = (gt == 2) ? (1.f - 2.f * rc) : rc;   // tanh : sigmoid
            float f_ = __shfl_xor(a, 4);
            float g_ = __shfl_xor(a, 8);
            float o_ = __shfl_xor(a, 12);
            float cv = f_ * c_reg[hf][m][r] + a * g_;
            c_reg[hf][m][r] = cv;
            float e2 = __expf(2.f * cv);
            float hv = o_ * (1.f - 2.f / (1.f + e2));
            u32 bits = f2bf(hv);
            u32 lo = bits | (((u32)__shfl_xor((int)bits, 1)) << 16);
            u32 hi = (u32)__shfl_xor((int)lo, 2);
            if (lr == 0){
              u64 pk = (u64)lo | ((u64)hi << 32);
              __hip_atomic_store((u64*)(hdst + (size_t)(m * 16 + lg * 4 + r) * 16 + w * 4), pk,
                                 __ATOMIC_RELAXED, __HIP_MEMORY_SCOPE_AGENT);
            }
          }
        }
      } else {
        // stage: poll flag for the half used NEXT slot, fetch 32KB, commit.
        // hf==0 -> next slot (t,1) uses h_t[1]:   flag[1] >= t,  buf t&1
        // hf==1 -> next slot (t+1,0) uses h_{t+1}[0]: flag[0] >= t+1, buf (t+1)&1
        const int hfT = hf ^ 1;
        const int tf  = t + hf;
        if (tf < ZT || hf == 0){
          if (!(t == 0 && hf == 0))          // h_0[1] needs no wait (zeros)
            qwait(flags, bg * 2 + hfT, (u32)tf);
          const u64* src = (const u64*)(hbuf + qoff2(tf & 1, bg, hfT, 0));
          u64 va[8], vb[8];
          #pragma unroll
          for (int i = 0; i < 8; ++i){
            int cc = st + i * 256;
            va[i] = aload(src + (size_t)cc * 2);
            vb[i] = aload(src + (size_t)cc * 2 + 1);
          }
          char* dst = (char*)hs2[hf ^ 1];
          #pragma unroll
          for (int i = 0; i < 8; ++i){
            int byte = (st + i * 256) * 16;
            int swz = byte ^ (((byte >> 5) & 3) << 4);
            *(s8v*)(dst + swz) = pair2v(va[i], vb[i]);
          }
        }
      }
      // slot end: full drain (syncthreads) then publish this half's flag
      __syncthreads();
      if (tid == 0)
        __hip_atomic_store(flbase + (size_t)hf * 512, (u32)(t + 1),
                           __ATOMIC_RELAXED, __HIP_MEMORY_SCOPE_AGENT);
    }
  }

  // epilogue: hg==0 blocks compute out = h_T @ Wfc^T + bfc (h_T in buf 0)
  if (hg == 0){
    if (tid < 64){
      qwait(flags, bg * 2 + 0, (u32)ZT);
      qwait(flags, bg * 2 + 1, (u32)ZT);
    }
    __syncthreads();
    if (isC){
      float ob = (lr < ZNC) ? bfc[lr] : 0.f;
      f4v acc = {ob, ob, ob, ob};
      const u16* wp = Wfcb + (size_t)lr * ZH + lg * 8;
      const int hfE = w >> 1;
      const int ric = (w & 1) * 16 + lr;     // row in 32-row chunk
      #pragma unroll
      for (int kt = 0; kt < 16; ++kt){
        int hgp = 2 * kt + (lg >> 1);
        const u64* hp = (const u64*)(hbuf + qoff2(0, bg, hfE, hgp) + (size_t)ric * 16 + (lg & 1) * 8);
        u64 a0 = aload(hp);
        u64 a1 = aload(hp + 1);
        s8v av = pair2v(a0, a1);
        s8v bv = *(const s8v*)(wp + kt * 32);
        acc = __builtin_amdgcn_mfma_f32_16x16x32_bf16(av, bv, acc, 0, 0, 0);
      }
      if (lr < ZNC){
        #pragma unroll
        for (int r = 0; r < 4; ++r)
          out[(size_t)(bg * 64 + w * 16 + lg * 4 + r) * ZNC + lr] = acc[r];
      }
    }
  }
}

// ---------------------------------------------------------------------------
extern "C" void kernel_launch(void* const* d_in, const int* in_sizes, int n_in,
                              void* d_out, int out_size, void* d_ws, size_t ws_size,
                              hipStream_t stream)
{
  const float* seq  = (const float*)d_in[0];
  const float* W1   = (const float*)d_in[1];
  const float* b1   = (const float*)d_in[2];
  const float* W2   = (const float*)d_in[3];
  const float* b2   = (const float*)d_in[4];
  const float* W_ih = (const float*)d_in[5];
  const float* W_hh = (const float*)d_in[6];
  const float* b_ih = (const float*)d_in[7];
  const float* b_hh = (const float*)d_in[8];
  const float* Wfc  = (const float*)d_in[9];
  const float* bfc  = (const float*)d_in[10];
  float* out = (float*)d_out;

  char* ws = (char*)d_ws;
  size_t off = 0;
  auto alloc = [&](size_t bytes){ void* p = ws + off; off += (bytes + 255) & ~(size_t)255; return p; };
  u16*   Wc    = (u16*)  alloc((size_t)ZG * ZEH * 2);
  float* bc    = (float*)alloc((size_t)ZG * 4);
  u16*   Whh   = (u16*)  alloc((size_t)ZG * ZH * 2);
  u16*   Wfcb  = (u16*)  alloc((size_t)16 * ZH * 2);
  u16*   X1    = (u16*)  alloc((size_t)ZB * ZT * ZEH * 2);
  u16*   hbuf  = (u16*)  alloc((size_t)2 * ZB * ZH * 2);
  u32*   flags = (u32*)  alloc((size_t)8 * 2 * 32 * 16 * 4);  // 64B-padded per (bg,hf,hg)

  hipMemsetAsync(flags, 0, (size_t)8 * 2 * 32 * 16 * 4, stream);
  hipMemsetAsync(hbuf, 0, (size_t)ZB * ZH * 2, stream);      // h_0 = 0 (buffer 0)
  hipMemsetAsync(Wfcb, 0, (size_t)16 * ZH * 2, stream);      // pad rows 8..15 = 0

  hipLaunchKernelGGL(k_fold, dim3(ZG), dim3(128), 0, stream, W_ih, W2, b2, b_ih, b_hh, Wc, bc);
  hipLaunchKernelGGL(k_cvt, dim3((ZG * ZH + 255) / 256), dim3(256), 0, stream, W_hh, Whh, ZG * ZH);
  hipLaunchKernelGGL(k_cvt, dim3((ZNC * ZH + 255) / 256), dim3(256), 0, stream, Wfc, Wfcb, ZNC * ZH);
  hipLaunchKernelGGL(k_enc, dim3(ZB * ZT / 64), dim3(256), 0, stream, seq, W1, b1, X1);
  hipLaunchKernelGGL(k_lstm, dim3(NBLK), dim3(512), 0, stream,
                     X1, Whh, Wc, bc, Wfcb, bfc, hbuf, out, flags);
}